// Round 7
// baseline (63.218 us; speedup 1.0000x reference)
//
#include <hip/hip_runtime.h>
#include <hip/hip_bf16.h>
#include <math.h>

// Problem dims (fixed per reference)
#define B_DIM 32
#define C_DIM 256
#define K_DIM 32
#define N_DIM 4096   // 64*64
#define NSLICE 32    // 128-px slices (4 waves x 32 px)
#define RSD 34       // dword stride per c-pair row (16 rows, 32 px + pad)

typedef short v8s __attribute__((ext_vector_type(8)));   // 8 bf16
typedef float v4f __attribute__((ext_vector_type(4)));   // MFMA acc

// ws float offsets — every slot overwritten each call, no zeroing, no atomics
//   [0,     32)      c2   [K]
//   [32,    4128)    cw_bf16 [K][C] as u16 (16 KB)
//   [4128,  266272)  Spart [B][32][C]
//   [266272,299040)  a_part[B][32][K]
#define WS_C2    0
#define WS_CWB   32
#define WS_SPART 4128
#define WS_APART 266272

__global__ __launch_bounds__(64)
void ce_prep(const float* __restrict__ cw, float* __restrict__ ws) {
    const int k    = blockIdx.x;    // 0..31
    const int lane = threadIdx.x;   // 0..63
    float4 v = ((const float4*)(cw + (size_t)k * C_DIM))[lane];
    union { unsigned short s[4]; uint2 d; } o;
    union { __hip_bfloat16 h; unsigned short u; } cv;
    cv.h = __float2bfloat16(v.x); o.s[0] = cv.u;
    cv.h = __float2bfloat16(v.y); o.s[1] = cv.u;
    cv.h = __float2bfloat16(v.z); o.s[2] = cv.u;
    cv.h = __float2bfloat16(v.w); o.s[3] = cv.u;
    unsigned short* cwb = (unsigned short*)(ws + WS_CWB);
    ((uint2*)(cwb + (size_t)k * C_DIM))[lane] = o.d;

    float sq = 0.f;
    sq = fmaf(v.x, v.x, sq); sq = fmaf(v.y, v.y, sq);
    sq = fmaf(v.z, v.z, sq); sq = fmaf(v.w, v.w, sq);
    sq += __shfl_xor(sq, 1);
    sq += __shfl_xor(sq, 2);
    sq += __shfl_xor(sq, 4);
    sq += __shfl_xor(sq, 8);
    sq += __shfl_xor(sq, 16);
    sq += __shfl_xor(sq, 32);
    if (lane == 0) ws[WS_C2 + k] = sq;
}

__global__ __launch_bounds__(256, 4)
void ce_main(const float* __restrict__ x,
             const float* __restrict__ scale,
             const float* __restrict__ ws_ro,
             float* __restrict__ Spart,
             float* __restrict__ a_part) {
    __shared__ float buf[2][4][16 * RSD];   // 17.4 KB wave-private dbuf tiles
    __shared__ float sA[4][C_DIM];          // 4 KB per-wave S partials
    __shared__ float awv[4][K_DIM];         // per-wave a partials
    __shared__ float f2s[4][32];            // per-wave f2 (32 px each)

    const int tid   = threadIdx.x;
    const int wave  = tid >> 6;
    const int lane  = tid & 63;
    const int g     = lane >> 4;    // 0..3
    const int m     = lane & 15;
    const int px    = lane & 31;    // this lane's pixel within the wave
    const int h     = lane >> 5;    // c-half loader role (0/1)
    const int slice = blockIdx.x;   // 0..31 (128 px)
    const int b     = blockIdx.y;   // 0..31

    // wave owns 32 px, all 256 c
    const float* xp = x + (size_t)b * C_DIM * N_DIM + slice * 128 + wave * 32
                        + (size_t)(16 * h) * N_DIM + px;
    const uint4* cwb4 = (const uint4*)(ws_ro + WS_CWB);
    const float* c2p  = ws_ro + WS_C2;

    float* b0 = &buf[0][wave][0];
    float* b1 = &buf[1][wave][0];

    v4f acc[2][2];
    #pragma unroll
    for (int u = 0; u < 2; ++u)
        #pragma unroll
        for (int t = 0; t < 2; ++t) acc[u][t] = (v4f){0.f, 0.f, 0.f, 0.f};

    float f2 = 0.f;
    float fA[8], fB[8];

    // A-frag prefetch (cw bf16): A row m -> k=16u+m, c-chunk 8g
    uint4 af0 = cwb4[m * 32 + g];
    uint4 af1 = cwb4[(16 + m) * 32 + g];

    // stage c-step 0: lane loads c = 16h+2j(+1) for its px
    #pragma unroll
    for (int j = 0; j < 8; ++j) {
        fA[j] = xp[(size_t)(2 * j) * N_DIM];
        fB[j] = xp[(size_t)(2 * j + 1) * N_DIM];
    }
    #pragma unroll
    for (int j = 0; j < 8; ++j) {
        f2 = fmaf(fA[j], fA[j], f2);
        f2 = fmaf(fB[j], fB[j], f2);
        union { __hip_bfloat16 h; unsigned short u; } lo, hi;
        lo.h = __float2bfloat16(fA[j]);
        hi.h = __float2bfloat16(fB[j]);
        ((unsigned*)b0)[(8 * h + j) * RSD + px] = ((unsigned)hi.u << 16) | lo.u;
    }

    #pragma unroll
    for (int s = 0; s < 8; ++s) {
        float* cb = (s & 1) ? b1 : b0;
        float* nb = (s & 1) ? b0 : b1;

        // issue next c-step's loads early (hidden under MFMA + S phases)
        uint4 naf0, naf1;
        if (s < 7) {
            naf0 = cwb4[m * 32 + 4 * (s + 1) + g];
            naf1 = cwb4[(16 + m) * 32 + 4 * (s + 1) + g];
            #pragma unroll
            for (int j = 0; j < 8; ++j) {
                fA[j] = xp[(size_t)(32 * (s + 1) + 2 * j) * N_DIM];
                fB[j] = xp[(size_t)(32 * (s + 1) + 2 * j + 1) * N_DIM];
            }
        }

        // B-frags + 4 MFMA: D[k][px] += cw[k][c] * f[c][px]
        #pragma unroll
        for (int t = 0; t < 2; ++t) {
            union { unsigned d[4]; v8s v; } fb;
            #pragma unroll
            for (int q = 0; q < 4; ++q)
                fb.d[q] = ((const unsigned*)cb)[(4 * g + q) * RSD + 16 * t + m];
            union { uint4 u; v8s v; } a0, a1;
            a0.u = af0; a1.u = af1;
            acc[0][t] = __builtin_amdgcn_mfma_f32_16x16x32_bf16(a0.v, fb.v, acc[0][t], 0, 0, 0);
            acc[1][t] = __builtin_amdgcn_mfma_f32_16x16x32_bf16(a1.v, fb.v, acc[1][t], 0, 0, 0);
        }

        // S row sums from the staged tile: lane role (row m, px-chunk 8g)
        {
            float aLo = 0.f, aHi = 0.f;
            #pragma unroll
            for (int q = 0; q < 4; ++q) {
                uint2 w = *(const uint2*)&((const unsigned*)cb)[m * RSD + 8 * g + 2 * q];
                aLo += __uint_as_float(w.x << 16) + __uint_as_float(w.y << 16);
                aHi += __uint_as_float(w.x & 0xffff0000u) + __uint_as_float(w.y & 0xffff0000u);
            }
            aLo += __shfl_xor(aLo, 16); aLo += __shfl_xor(aLo, 32);
            aHi += __shfl_xor(aHi, 16); aHi += __shfl_xor(aHi, 32);
            if (lane < 16) {
                sA[wave][32 * s + 2 * m]     = aLo;
                sA[wave][32 * s + 2 * m + 1] = aHi;
            }
        }

        // pack + write next tile (waits on the global loads issued above)
        if (s < 7) {
            #pragma unroll
            for (int j = 0; j < 8; ++j) {
                f2 = fmaf(fA[j], fA[j], f2);
                f2 = fmaf(fB[j], fB[j], f2);
                union { __hip_bfloat16 h; unsigned short u; } lo, hi;
                lo.h = __float2bfloat16(fA[j]);
                hi.h = __float2bfloat16(fB[j]);
                ((unsigned*)nb)[(8 * h + j) * RSD + px] = ((unsigned)hi.u << 16) | lo.u;
            }
            af0 = naf0; af1 = naf1;
        }
    }

    // ---- epilogue (all wave-local until the single barrier) ----
    // f2 total per px: combine the two c-half loader lanes
    f2 += __shfl_xor(f2, 32);
    if (h == 0) f2s[wave][px] = f2;

    float c2v[2][4], scv[2][4];
    #pragma unroll
    for (int u = 0; u < 2; ++u)
        #pragma unroll
        for (int r = 0; r < 4; ++r) {
            int k = 16 * u + 4 * g + r;
            c2v[u][r] = c2p[k];
            scv[u][r] = scale[k];
        }

    float aacc[2][4] = {{0.f,0.f,0.f,0.f},{0.f,0.f,0.f,0.f}};
    #pragma unroll
    for (int t = 0; t < 2; ++t) {
        float f2t = f2s[wave][16 * t + m];   // px = 16t + m
        float L[2][4];
        float mx = -1e30f;
        #pragma unroll
        for (int u = 0; u < 2; ++u)
            #pragma unroll
            for (int r = 0; r < 4; ++r) {
                float d2 = f2t + c2v[u][r] - 2.f * acc[u][t][r];
                float dist = sqrtf(fmaxf(d2, 0.f));
                float Lv = -dist * scv[u][r];
                L[u][r] = Lv;
                mx = fmaxf(mx, Lv);
            }
        mx = fmaxf(mx, __shfl_xor(mx, 16));
        mx = fmaxf(mx, __shfl_xor(mx, 32));
        float e[2][4], ss = 0.f;
        #pragma unroll
        for (int u = 0; u < 2; ++u)
            #pragma unroll
            for (int r = 0; r < 4; ++r) {
                e[u][r] = __expf(L[u][r] - mx);
                ss += e[u][r];
            }
        ss += __shfl_xor(ss, 16);
        ss += __shfl_xor(ss, 32);
        float inv = 1.f / ss;
        #pragma unroll
        for (int u = 0; u < 2; ++u)
            #pragma unroll
            for (int r = 0; r < 4; ++r)
                aacc[u][r] = fmaf(e[u][r], inv, aacc[u][r]);
    }

    // reduce a over the 16 m-lanes (covers both t pixels)
    #pragma unroll
    for (int u = 0; u < 2; ++u)
        #pragma unroll
        for (int r = 0; r < 4; ++r) {
            float v = aacc[u][r];
            v += __shfl_xor(v, 1);
            v += __shfl_xor(v, 2);
            v += __shfl_xor(v, 4);
            v += __shfl_xor(v, 8);
            if (m == 0) awv[wave][16 * u + 4 * g + r] = v;
        }
    __syncthreads();

    // cross-wave combine: waves hold disjoint px, same c/k ranges
    float Ssum = sA[0][tid] + sA[1][tid] + sA[2][tid] + sA[3][tid];
    Spart[((size_t)b * NSLICE + slice) * C_DIM + tid] = Ssum;
    if (tid < K_DIM)
        a_part[((size_t)b * NSLICE + slice) * K_DIM + tid] =
            awv[0][tid] + awv[1][tid] + awv[2][tid] + awv[3][tid];
}

__global__ void ce_final(float* __restrict__ out,
                         const float* __restrict__ cw,
                         const float* __restrict__ Spart,
                         const float* __restrict__ a_part) {
    __shared__ float asum[K_DIM];
    const int b = blockIdx.x;
    const int c = threadIdx.x;

    if (c < K_DIM) {
        float a = 0.f;
        #pragma unroll
        for (int s = 0; s < NSLICE; ++s)
            a += a_part[((size_t)b * NSLICE + s) * K_DIM + c];
        asum[c] = a;
    }
    __syncthreads();

    float S = 0.f;
    #pragma unroll
    for (int s = 0; s < NSLICE; ++s)
        S += Spart[((size_t)b * NSLICE + s) * C_DIM + c];

    float acc2 = 0.f;
    #pragma unroll
    for (int k = 0; k < K_DIM; ++k)
        acc2 = fmaf(asum[k], cw[k * C_DIM + c], acc2);  // coalesced over c
    out[b * C_DIM + c] = (S - acc2) * (1.0f / (float)K_DIM);
}

extern "C" void kernel_launch(void* const* d_in, const int* in_sizes, int n_in,
                              void* d_out, int out_size, void* d_ws, size_t ws_size,
                              hipStream_t stream) {
    const float* x     = (const float*)d_in[0];
    const float* cw    = (const float*)d_in[1];
    const float* scale = (const float*)d_in[2];
    float* out = (float*)d_out;
    float* ws  = (float*)d_ws;

    ce_prep<<<K_DIM, 64, 0, stream>>>(cw, ws);

    dim3 grid(NSLICE, B_DIM);
    ce_main<<<grid, 256, 0, stream>>>(x, scale, ws,
                                      ws + WS_SPART, ws + WS_APART);

    ce_final<<<B_DIM, 256, 0, stream>>>(out, cw,
                                        ws + WS_SPART, ws + WS_APART);
}

// Round 8
// 59.672 us; speedup vs baseline: 1.0594x; 1.0594x over previous
//
#include <hip/hip_runtime.h>
#include <hip/hip_bf16.h>
#include <math.h>

// Problem dims (fixed per reference)
#define B_DIM 32
#define C_DIM 256
#define K_DIM 32
#define N_DIM 4096   // 64*64
#define NSLICE 16    // 256-px slices (4 waves x 64 px)

typedef short v8s __attribute__((ext_vector_type(8)));   // 8 bf16
typedef float v4f __attribute__((ext_vector_type(4)));   // MFMA acc

// ws float offsets — every slot overwritten each call, no zeroing, no atomics
//   [0,    32)      c2   [K]
//   [32,   4128)    cw_bf16 [K][C] as u16 (16 KB)
//   [4128, 135200)  Spart [B][16][C]
//   [135200,151584) a_part[B][16][K]
#define WS_C2    0
#define WS_CWB   32
#define WS_SPART 4128
#define WS_APART 135200

__global__ __launch_bounds__(64)
void ce_prep(const float* __restrict__ cw, float* __restrict__ ws) {
    const int k    = blockIdx.x;    // 0..31
    const int lane = threadIdx.x;   // 0..63
    float4 v = ((const float4*)(cw + (size_t)k * C_DIM))[lane];
    union { unsigned short s[4]; uint2 d; } o;
    union { __hip_bfloat16 h; unsigned short u; } cv;
    cv.h = __float2bfloat16(v.x); o.s[0] = cv.u;
    cv.h = __float2bfloat16(v.y); o.s[1] = cv.u;
    cv.h = __float2bfloat16(v.z); o.s[2] = cv.u;
    cv.h = __float2bfloat16(v.w); o.s[3] = cv.u;
    unsigned short* cwb = (unsigned short*)(ws + WS_CWB);
    ((uint2*)(cwb + (size_t)k * C_DIM))[lane] = o.d;

    float sq = 0.f;
    sq = fmaf(v.x, v.x, sq); sq = fmaf(v.y, v.y, sq);
    sq = fmaf(v.z, v.z, sq); sq = fmaf(v.w, v.w, sq);
    sq += __shfl_xor(sq, 1);
    sq += __shfl_xor(sq, 2);
    sq += __shfl_xor(sq, 4);
    sq += __shfl_xor(sq, 8);
    sq += __shfl_xor(sq, 16);
    sq += __shfl_xor(sq, 32);
    if (lane == 0) ws[WS_C2 + k] = sq;
}

__device__ __forceinline__ void wait_vm8() {
    asm volatile("s_waitcnt vmcnt(8)" ::: "memory");
    __builtin_amdgcn_sched_barrier(0);
}
__device__ __forceinline__ void wait_vm4() {
    asm volatile("s_waitcnt vmcnt(4)" ::: "memory");
    __builtin_amdgcn_sched_barrier(0);
}
__device__ __forceinline__ void wait_vm0() {
    asm volatile("s_waitcnt vmcnt(0)" ::: "memory");
    __builtin_amdgcn_sched_barrier(0);
}

// One c-step: consume one 32c x 32px fp32 tile from LDS.
// PH = px-half (0/1); s = c-step (0..7); runtime-safe except acc/f2p indices.
template<int PH>
__device__ __forceinline__ void consume_step(
    const float* __restrict__ cb, int s, int g, int m,
    const unsigned* __restrict__ cwlm, const unsigned* __restrict__ cwlm16,
    int col0, int col1, float* __restrict__ sSw,
    v4f (&acc)[2][4], float (&f2p)[4]) {

    union { uint4 u; v8s v; } a0, a1;
    a0.u = *(const uint4*)&cwlm [16 * s + 4 * g];
    a1.u = *(const uint4*)&cwlm16[16 * s + 4 * g];

    float Sp[8] = {0.f, 0.f, 0.f, 0.f, 0.f, 0.f, 0.f, 0.f};
    const int rowbase = g * 256;   // (8g)*32 dwords

    #pragma unroll
    for (int t = 0; t < 2; ++t) {
        const int col = t ? col1 : col0;
        float v[8];
        #pragma unroll
        for (int i = 0; i < 8; ++i) v[i] = cb[rowbase + 32 * i + col];
        #pragma unroll
        for (int i = 0; i < 8; ++i) {
            f2p[2 * PH + t] = fmaf(v[i], v[i], f2p[2 * PH + t]);
            Sp[i] += v[i];
        }
        union { unsigned d[4]; v8s v8; } fb;
        #pragma unroll
        for (int h = 0; h < 4; ++h) {
            union { __hip_bfloat16 bh; unsigned short u; } lo, hi;
            lo.bh = __float2bfloat16(v[2 * h]);
            hi.bh = __float2bfloat16(v[2 * h + 1]);
            fb.d[h] = ((unsigned)hi.u << 16) | lo.u;
        }
        acc[0][2 * PH + t] = __builtin_amdgcn_mfma_f32_16x16x32_bf16(a0.v, fb.v8, acc[0][2 * PH + t], 0, 0, 0);
        acc[1][2 * PH + t] = __builtin_amdgcn_mfma_f32_16x16x32_bf16(a1.v, fb.v8, acc[1][2 * PH + t], 0, 0, 0);
    }

    // S[c]: reduce over the 16 m-lanes, accumulate into per-wave LDS
    #pragma unroll
    for (int i = 0; i < 8; ++i) {
        Sp[i] += __shfl_xor(Sp[i], 1);
        Sp[i] += __shfl_xor(Sp[i], 2);
        Sp[i] += __shfl_xor(Sp[i], 4);
        Sp[i] += __shfl_xor(Sp[i], 8);
    }
    if (m == 0) {
        float* sp = sSw + 32 * s + 8 * g;
        float4 o0 = *(float4*)sp, o1 = *((float4*)sp + 1);
        o0.x += Sp[0]; o0.y += Sp[1]; o0.z += Sp[2]; o0.w += Sp[3];
        o1.x += Sp[4]; o1.y += Sp[5]; o1.z += Sp[6]; o1.w += Sp[7];
        *(float4*)sp = o0; *((float4*)sp + 1) = o1;
    }
}

__global__ __launch_bounds__(256, 2)
void ce_main(const float* __restrict__ x,
             const float* __restrict__ scale,
             const float* __restrict__ ws_ro,
             float* __restrict__ Spart,
             float* __restrict__ a_part) {
    __shared__ float buf[3][4][1024];      // 48 KB: 3-ring x 4 waves x (32c x 32px) fp32
    __shared__ unsigned cwl[K_DIM][132];   // 16.5 KB cw bf16-pairs, padded rows
    __shared__ float sS[4][C_DIM];         // 4 KB per-wave S accumulators
    __shared__ float awv[4][K_DIM];        // 0.5 KB per-wave a partials
    __shared__ float csl[64];              // c2[32] ++ scale[32]

    const int tid   = threadIdx.x;
    const int wave  = tid >> 6;
    const int lane  = tid & 63;
    const int g     = lane >> 4;
    const int m     = lane & 15;
    const int slice = blockIdx.x;   // 0..15 (256 px)
    const int b     = blockIdx.y;   // 0..31

    // ---- phase 0: stage cw / c2 / scale into LDS (all plain VMEM, fully
    // drained by the barrier BEFORE any DMA is issued -> clean vmcnt stream)
    {
        const uint4* cwb4 = (const uint4*)(ws_ro + WS_CWB);
        const int row = tid >> 3, seg = tid & 7;
        #pragma unroll
        for (int j = 0; j < 4; ++j) {
            uint4 v = cwb4[row * 32 + seg * 4 + j];
            *(uint4*)&cwl[row][seg * 16 + 4 * j] = v;
        }
        if (tid < 32) csl[tid] = ws_ro[WS_C2 + tid];
        else if (tid < 64) csl[tid] = scale[tid - 32];
    }
    __syncthreads();

    // zero this wave's S accumulator (wave-private, no barrier needed)
    #pragma unroll
    for (int j = 0; j < 4; ++j) sS[wave][j * 64 + lane] = 0.f;

    const float* xw = x + (size_t)b * C_DIM * N_DIM + slice * 256 + wave * 64;
    float* sSw = &sS[wave][0];
    const unsigned* cwlm   = &cwl[m][0];
    const unsigned* cwlm16 = &cwl[16 + m][0];

    // swizzled column offsets for B-frag reads (t = 0,1)
    const int xr   = (g & 1) << 2;
    const int col0 = ((((m >> 2) + 0) ^ xr) << 2) + (m & 3);
    const int col1 = ((((m >> 2) + 4) ^ xr) << 2) + (m & 3);

    // stage tile q (q = ph*8 + s) into ring slot q%3 via async DMA.
    // LDS dst linear; global source pre-swizzled (chunk ^ ((row>>3)&1)<<2).
    auto stage = [&](int q) {
        const int ph = q >> 3, s = q & 7;
        const float* bp = xw + ph * 32;
        float* dst = &buf[q % 3][wave][0];
        #pragma unroll
        for (int ir = 0; ir < 4; ++ir) {
            const int row   = 8 * ir + (lane >> 3);
            const int chunk = (lane & 7) ^ ((ir & 1) << 2);
            const float* src = bp + (size_t)(s * 32 + row) * N_DIM + chunk * 4;
            __builtin_amdgcn_global_load_lds(
                (const __attribute__((address_space(1))) void*)src,
                (__attribute__((address_space(3))) void*)(dst + ir * 256),
                16, 0, 0);
        }
    };

    v4f acc[2][4];
    #pragma unroll
    for (int u = 0; u < 2; ++u)
        #pragma unroll
        for (int t = 0; t < 4; ++t) acc[u][t] = (v4f){0.f, 0.f, 0.f, 0.f};
    float f2p[4] = {0.f, 0.f, 0.f, 0.f};

    stage(0);
    stage(1);

    // px-half 0: tiles q = 0..7 (always 2 tiles in flight -> vmcnt(8))
    #pragma unroll
    for (int s = 0; s < 8; ++s) {
        stage(s + 2);
        wait_vm8();
        consume_step<0>(&buf[s % 3][wave][0], s, g, m, cwlm, cwlm16,
                        col0, col1, sSw, acc, f2p);
    }
    // px-half 1: tiles q = 8..15
    #pragma unroll
    for (int s = 0; s < 8; ++s) {
        const int q = 8 + s;
        if (s < 6) { stage(q + 2); wait_vm8(); }
        else if (s == 6) wait_vm4();
        else wait_vm0();
        consume_step<1>(&buf[q % 3][wave][0], s, g, m, cwlm, cwlm16,
                        col0, col1, sSw, acc, f2p);
    }

    // ---- epilogue (wave-local until the single barrier) ----
    #pragma unroll
    for (int tt = 0; tt < 4; ++tt) {
        f2p[tt] += __shfl_xor(f2p[tt], 16);
        f2p[tt] += __shfl_xor(f2p[tt], 32);
    }

    float c2v[2][4], scv[2][4];
    #pragma unroll
    for (int u = 0; u < 2; ++u)
        #pragma unroll
        for (int r = 0; r < 4; ++r) {
            int k = 16 * u + 4 * g + r;
            c2v[u][r] = csl[k];
            scv[u][r] = csl[32 + k];
        }

    float aacc[2][4] = {{0.f,0.f,0.f,0.f},{0.f,0.f,0.f,0.f}};
    #pragma unroll
    for (int tt = 0; tt < 4; ++tt) {
        float L[2][4];
        float mx = -1e30f;
        #pragma unroll
        for (int u = 0; u < 2; ++u)
            #pragma unroll
            for (int r = 0; r < 4; ++r) {
                float d2 = f2p[tt] + c2v[u][r] - 2.f * acc[u][tt][r];
                float dist = sqrtf(fmaxf(d2, 0.f));
                float Lv = -dist * scv[u][r];
                L[u][r] = Lv;
                mx = fmaxf(mx, Lv);
            }
        mx = fmaxf(mx, __shfl_xor(mx, 16));
        mx = fmaxf(mx, __shfl_xor(mx, 32));
        float e[2][4], ss = 0.f;
        #pragma unroll
        for (int u = 0; u < 2; ++u)
            #pragma unroll
            for (int r = 0; r < 4; ++r) {
                e[u][r] = __expf(L[u][r] - mx);
                ss += e[u][r];
            }
        ss += __shfl_xor(ss, 16);
        ss += __shfl_xor(ss, 32);
        float inv = 1.f / ss;
        #pragma unroll
        for (int u = 0; u < 2; ++u)
            #pragma unroll
            for (int r = 0; r < 4; ++r)
                aacc[u][r] = fmaf(e[u][r], inv, aacc[u][r]);
    }

    // reduce a over the 16 m-lanes (covers all 4 px-tiles)
    #pragma unroll
    for (int u = 0; u < 2; ++u)
        #pragma unroll
        for (int r = 0; r < 4; ++r) {
            float v = aacc[u][r];
            v += __shfl_xor(v, 1);
            v += __shfl_xor(v, 2);
            v += __shfl_xor(v, 4);
            v += __shfl_xor(v, 8);
            if (m == 0) awv[wave][16 * u + 4 * g + r] = v;
        }
    __syncthreads();

    // cross-wave combine: waves hold disjoint px, same c/k ranges
    float Ssum = sS[0][tid] + sS[1][tid] + sS[2][tid] + sS[3][tid];
    Spart[((size_t)b * NSLICE + slice) * C_DIM + tid] = Ssum;
    if (tid < K_DIM)
        a_part[((size_t)b * NSLICE + slice) * K_DIM + tid] =
            awv[0][tid] + awv[1][tid] + awv[2][tid] + awv[3][tid];
}

__global__ void ce_final(float* __restrict__ out,
                         const float* __restrict__ cw,
                         const float* __restrict__ Spart,
                         const float* __restrict__ a_part) {
    __shared__ float asum[K_DIM];
    const int b = blockIdx.x;
    const int c = threadIdx.x;

    if (c < K_DIM) {
        float a = 0.f;
        #pragma unroll
        for (int s = 0; s < NSLICE; ++s)
            a += a_part[((size_t)b * NSLICE + s) * K_DIM + c];
        asum[c] = a;
    }
    __syncthreads();

    float S = 0.f;
    #pragma unroll
    for (int s = 0; s < NSLICE; ++s)
        S += Spart[((size_t)b * NSLICE + s) * C_DIM + c];

    float acc2 = 0.f;
    #pragma unroll
    for (int k = 0; k < K_DIM; ++k)
        acc2 = fmaf(asum[k], cw[k * C_DIM + c], acc2);  // coalesced over c
    out[b * C_DIM + c] = (S - acc2) * (1.0f / (float)K_DIM);
}

extern "C" void kernel_launch(void* const* d_in, const int* in_sizes, int n_in,
                              void* d_out, int out_size, void* d_ws, size_t ws_size,
                              hipStream_t stream) {
    const float* x     = (const float*)d_in[0];
    const float* cw    = (const float*)d_in[1];
    const float* scale = (const float*)d_in[2];
    float* out = (float*)d_out;
    float* ws  = (float*)d_ws;

    ce_prep<<<K_DIM, 64, 0, stream>>>(cw, ws);

    dim3 grid(NSLICE, B_DIM);
    ce_main<<<grid, 256, 0, stream>>>(x, scale, ws,
                                      ws + WS_SPART, ws + WS_APART);

    ce_final<<<B_DIM, 256, 0, stream>>>(out, cw,
                                        ws + WS_SPART, ws + WS_APART);
}

// Round 9
// 46.568 us; speedup vs baseline: 1.3575x; 1.2814x over previous
//
#include <hip/hip_runtime.h>
#include <hip/hip_bf16.h>
#include <math.h>

// Problem dims (fixed per reference)
#define B_DIM 32
#define C_DIM 256
#define K_DIM 32
#define N_DIM 4096   // 64*64
#define NSLICE 16    // 256-px slices (4 waves x 64 px)
#define RS 66        // padded dword stride per c-pair row (16 rows/tile)

typedef short v8s __attribute__((ext_vector_type(8)));   // 8 bf16
typedef float v4f __attribute__((ext_vector_type(4)));   // MFMA acc

// ws float offsets — every slot overwritten each call, no zeroing, no atomics
//   [0,    32)      c2   [K]
//   [32,   4128)    cw_bf16 [K][C] as u16 (16 KB)
//   [4128, 135200)  Spart [B][16][C]
//   [135200,151584) a_part[B][16][K]
#define WS_C2    0
#define WS_CWB   32
#define WS_SPART 4128
#define WS_APART 135200

__global__ __launch_bounds__(64)
void ce_prep(const float* __restrict__ cw, float* __restrict__ ws) {
    const int k    = blockIdx.x;    // 0..31
    const int lane = threadIdx.x;   // 0..63
    float4 v = ((const float4*)(cw + (size_t)k * C_DIM))[lane];
    union { unsigned short s[4]; uint2 d; } o;
    union { __hip_bfloat16 h; unsigned short u; } cv;
    cv.h = __float2bfloat16(v.x); o.s[0] = cv.u;
    cv.h = __float2bfloat16(v.y); o.s[1] = cv.u;
    cv.h = __float2bfloat16(v.z); o.s[2] = cv.u;
    cv.h = __float2bfloat16(v.w); o.s[3] = cv.u;
    unsigned short* cwb = (unsigned short*)(ws + WS_CWB);
    ((uint2*)(cwb + (size_t)k * C_DIM))[lane] = o.d;

    float sq = 0.f;
    sq = fmaf(v.x, v.x, sq); sq = fmaf(v.y, v.y, sq);
    sq = fmaf(v.z, v.z, sq); sq = fmaf(v.w, v.w, sq);
    sq += __shfl_xor(sq, 1);
    sq += __shfl_xor(sq, 2);
    sq += __shfl_xor(sq, 4);
    sq += __shfl_xor(sq, 8);
    sq += __shfl_xor(sq, 16);
    sq += __shfl_xor(sq, 32);
    if (lane == 0) ws[WS_C2 + k] = sq;
}

__global__ __launch_bounds__(256, 2)
void ce_main(const float* __restrict__ x,
             const float* __restrict__ scale,
             const float* __restrict__ ws_ro,
             float* __restrict__ Spart,
             float* __restrict__ a_part) {
    __shared__ float buf[2][4][16 * RS];   // 33 KB: per-wave double-buffered tiles
    __shared__ float sA[4][C_DIM];         // per-wave S partials
    __shared__ float awv[4][K_DIM];        // per-wave a partials
    __shared__ float f2s[4][64];           // per-wave f2 redistribution

    const int tid   = threadIdx.x;
    const int wave  = tid >> 6;
    const int lane  = tid & 63;
    const int g     = lane >> 4;   // 16-lane group
    const int m     = lane & 15;
    const int slice = blockIdx.x;  // 0..15
    const int b     = blockIdx.y;  // 0..31

    const float* xw   = x + (size_t)b * C_DIM * N_DIM + slice * 256 + wave * 64;
    const uint4* cwb4 = (const uint4*)(ws_ro + WS_CWB);
    const float* c2p  = ws_ro + WS_C2;

    float* b0 = &buf[0][wave][0];
    float* b1 = &buf[1][wave][0];

    v4f acc[2][4];
    #pragma unroll
    for (int u = 0; u < 2; ++u)
        #pragma unroll
        for (int t = 0; t < 4; ++t) acc[u][t] = (v4f){0.f, 0.f, 0.f, 0.f};

    float f2 = 0.f;
    float sLo[8], sHi[8];
    float fA[2][16], fB[2][16];   // two in-flight register load sets

    // A-fragment prefetch for s=0 (cw bf16, k = 16u+m, c = 8g..8g+7)
    uint4 af0 = cwb4[m * 32 + g];
    uint4 af1 = cwb4[(16 + m) * 32 + g];

    // prologue: load step0 -> set0, pack to tile0; load step1 -> set1
    #pragma unroll
    for (int i = 0; i < 16; ++i) {
        fA[0][i] = xw[(size_t)(2 * i) * N_DIM + lane];
        fB[0][i] = xw[(size_t)(2 * i + 1) * N_DIM + lane];
    }
    #pragma unroll
    for (int i = 0; i < 16; ++i) {
        f2 = fmaf(fA[0][i], fA[0][i], f2);
        f2 = fmaf(fB[0][i], fB[0][i], f2);
        union { __hip_bfloat16 h; unsigned short u; } lo, hi;
        lo.h = __float2bfloat16(fA[0][i]);
        hi.h = __float2bfloat16(fB[0][i]);
        ((unsigned*)b0)[i * RS + lane] = ((unsigned)hi.u << 16) | lo.u;
    }
    #pragma unroll
    for (int i = 0; i < 16; ++i) {
        fA[1][i] = xw[(size_t)(32 + 2 * i) * N_DIM + lane];
        fB[1][i] = xw[(size_t)(32 + 2 * i + 1) * N_DIM + lane];
    }

    #pragma unroll
    for (int s = 0; s < 8; ++s) {
        float* cb = (s & 1) ? b1 : b0;        // tile for step s
        float* nb = (s & 1) ? b0 : b1;        // tile for step s+1

        // A-frag prefetch for s+1
        uint4 naf0, naf1;
        if (s < 7) {
            naf0 = cwb4[m * 32 + 4 * (s + 1) + g];
            naf1 = cwb4[(16 + m) * 32 + 4 * (s + 1) + g];
        }

        // issue HALF the loads for step s+2 into set[s&1] (2-step lookahead)
        if (s < 6) {
            #pragma unroll
            for (int i = 0; i < 16; ++i)
                fA[s & 1][i] = xw[(size_t)(32 * (s + 2) + 2 * i) * N_DIM + lane];
        }

        // B-frags (f) + 8 MFMA: D[k][px] += cw[k][c] * f[c][px]
        #pragma unroll
        for (int t = 0; t < 4; ++t) {
            union { unsigned d[4]; v8s v; } fb;
            #pragma unroll
            for (int h = 0; h < 4; ++h)
                fb.d[h] = ((const unsigned*)cb)[(4 * g + h) * RS + 16 * t + m];
            union { uint4 u; v8s v; } a0, a1;
            a0.u = af0; a1.u = af1;
            acc[0][t] = __builtin_amdgcn_mfma_f32_16x16x32_bf16(a0.v, fb.v, acc[0][t], 0, 0, 0);
            acc[1][t] = __builtin_amdgcn_mfma_f32_16x16x32_bf16(a1.v, fb.v, acc[1][t], 0, 0, 0);
        }

        // S row sums from the staged tile: lane owns row m, dword chunk 16g..16g+15
        {
            float aLo = 0.f, aHi = 0.f;
            #pragma unroll
            for (int q = 0; q < 8; ++q) {
                uint2 w = ((const uint2*)cb)[33 * m + 8 * g + q];
                aLo += __uint_as_float(w.x << 16) + __uint_as_float(w.y << 16);
                aHi += __uint_as_float(w.x & 0xffff0000u) + __uint_as_float(w.y & 0xffff0000u);
            }
            aLo += __shfl_xor(aLo, 16); aLo += __shfl_xor(aLo, 32);
            aHi += __shfl_xor(aHi, 16); aHi += __shfl_xor(aHi, 32);
            sLo[s] = aLo; sHi[s] = aHi;
        }

        // second half of the step s+2 loads
        if (s < 6) {
            #pragma unroll
            for (int i = 0; i < 16; ++i)
                fB[s & 1][i] = xw[(size_t)(32 * (s + 2) + 2 * i + 1) * N_DIM + lane];
        }

        // pack set[(s+1)&1] (loaded ~1.5 steps ago) -> next tile
        if (s < 7) {
            const int p = (s + 1) & 1;
            #pragma unroll
            for (int i = 0; i < 16; ++i) {
                f2 = fmaf(fA[p][i], fA[p][i], f2);
                f2 = fmaf(fB[p][i], fB[p][i], f2);
                union { __hip_bfloat16 h; unsigned short u; } lo, hi;
                lo.h = __float2bfloat16(fA[p][i]);
                hi.h = __float2bfloat16(fB[p][i]);
                ((unsigned*)nb)[i * RS + lane] = ((unsigned)hi.u << 16) | lo.u;
            }
            af0 = naf0; af1 = naf1;
        }
    }

    // ---- epilogue: softmax over k (4-lane groups share a pixel) ----
    f2s[wave][lane] = f2;

    float c2v[2][4], scv[2][4];
    #pragma unroll
    for (int u = 0; u < 2; ++u)
        #pragma unroll
        for (int r = 0; r < 4; ++r) {
            int k = 16 * u + 4 * g + r;
            c2v[u][r] = c2p[k];
            scv[u][r] = scale[k];
        }

    float aacc[2][4] = {{0.f,0.f,0.f,0.f},{0.f,0.f,0.f,0.f}};
    #pragma unroll
    for (int t = 0; t < 4; ++t) {
        float f2t = f2s[wave][16 * t + m];   // px = 16t + m
        float L[2][4];
        float mx = -1e30f;
        #pragma unroll
        for (int u = 0; u < 2; ++u)
            #pragma unroll
            for (int r = 0; r < 4; ++r) {
                float d2 = f2t + c2v[u][r] - 2.f * acc[u][t][r];
                float dist = sqrtf(fmaxf(d2, 0.f));
                float Lv = -dist * scv[u][r];
                L[u][r] = Lv;
                mx = fmaxf(mx, Lv);
            }
        mx = fmaxf(mx, __shfl_xor(mx, 16));
        mx = fmaxf(mx, __shfl_xor(mx, 32));
        float e[2][4], ss = 0.f;
        #pragma unroll
        for (int u = 0; u < 2; ++u)
            #pragma unroll
            for (int r = 0; r < 4; ++r) {
                e[u][r] = __expf(L[u][r] - mx);
                ss += e[u][r];
            }
        ss += __shfl_xor(ss, 16);
        ss += __shfl_xor(ss, 32);
        float inv = 1.f / ss;
        #pragma unroll
        for (int u = 0; u < 2; ++u)
            #pragma unroll
            for (int r = 0; r < 4; ++r)
                aacc[u][r] = fmaf(e[u][r], inv, aacc[u][r]);
    }

    // reduce a over the 16 pixels (m lanes) of each group
    #pragma unroll
    for (int u = 0; u < 2; ++u)
        #pragma unroll
        for (int r = 0; r < 4; ++r) {
            float v = aacc[u][r];
            v += __shfl_xor(v, 1);
            v += __shfl_xor(v, 2);
            v += __shfl_xor(v, 4);
            v += __shfl_xor(v, 8);
            if (m == 0) awv[wave][16 * u + 4 * g + r] = v;
        }

    if (g == 0) {
        #pragma unroll
        for (int s = 0; s < 8; ++s) {
            sA[wave][32 * s + 2 * m]     = sLo[s];
            sA[wave][32 * s + 2 * m + 1] = sHi[s];
        }
    }
    __syncthreads();

    float Ssum = sA[0][tid] + sA[1][tid] + sA[2][tid] + sA[3][tid];
    Spart[((size_t)b * NSLICE + slice) * C_DIM + tid] = Ssum;
    if (tid < K_DIM)
        a_part[((size_t)b * NSLICE + slice) * K_DIM + tid] =
            awv[0][tid] + awv[1][tid] + awv[2][tid] + awv[3][tid];
}

__global__ void ce_final(float* __restrict__ out,
                         const float* __restrict__ cw,
                         const float* __restrict__ Spart,
                         const float* __restrict__ a_part) {
    __shared__ float asum[K_DIM];
    const int b = blockIdx.x;
    const int c = threadIdx.x;

    if (c < K_DIM) {
        float a = 0.f;
        #pragma unroll
        for (int s = 0; s < NSLICE; ++s)
            a += a_part[((size_t)b * NSLICE + s) * K_DIM + c];
        asum[c] = a;
    }
    __syncthreads();

    float S = 0.f;
    #pragma unroll
    for (int s = 0; s < NSLICE; ++s)
        S += Spart[((size_t)b * NSLICE + s) * C_DIM + c];

    float acc2 = 0.f;
    #pragma unroll
    for (int k = 0; k < K_DIM; ++k)
        acc2 = fmaf(asum[k], cw[k * C_DIM + c], acc2);  // coalesced over c
    out[b * C_DIM + c] = (S - acc2) * (1.0f / (float)K_DIM);
}

extern "C" void kernel_launch(void* const* d_in, const int* in_sizes, int n_in,
                              void* d_out, int out_size, void* d_ws, size_t ws_size,
                              hipStream_t stream) {
    const float* x     = (const float*)d_in[0];
    const float* cw    = (const float*)d_in[1];
    const float* scale = (const float*)d_in[2];
    float* out = (float*)d_out;
    float* ws  = (float*)d_ws;

    ce_prep<<<K_DIM, 64, 0, stream>>>(cw, ws);

    dim3 grid(NSLICE, B_DIM);
    ce_main<<<grid, 256, 0, stream>>>(x, scale, ws,
                                      ws + WS_SPART, ws + WS_APART);

    ce_final<<<B_DIM, 256, 0, stream>>>(out, cw,
                                        ws + WS_SPART, ws + WS_APART);
}

// Round 12
// 44.833 us; speedup vs baseline: 1.4101x; 1.0387x over previous
//
#include <hip/hip_runtime.h>
#include <hip/hip_bf16.h>
#include <math.h>

// Problem dims (fixed per reference)
#define B_DIM 32
#define C_DIM 256
#define K_DIM 32
#define N_DIM 4096   // 64*64
#define NSLICE 16    // 256-px slices (4 waves x 64 px)
#define RS 66        // padded dword stride per c-pair row (16 rows/tile)

typedef short v8s __attribute__((ext_vector_type(8)));   // 8 bf16
typedef float v4f __attribute__((ext_vector_type(4)));   // MFMA acc

// ws float offsets — every slot overwritten each call, no zeroing, no atomics
//   [0,    32)      c2   [K]
//   [32,   4128)    cw_bf16 [K][C] as u16 (16 KB)
//   [4128, 135200)  Spart [B][16][C]
//   [135200,151584) a_part[B][16][K]
#define WS_C2    0
#define WS_CWB   32
#define WS_SPART 4128
#define WS_APART 135200

__device__ __forceinline__ unsigned pack_bf16(float lo, float hi) {
    union { __hip_bfloat16 h; unsigned short u; } a, b;
    a.h = __float2bfloat16(lo);
    b.h = __float2bfloat16(hi);
    return ((unsigned)b.u << 16) | a.u;
}

__global__ __launch_bounds__(64)
void ce_prep(const float* __restrict__ cw, float* __restrict__ ws) {
    const int k    = blockIdx.x;    // 0..31
    const int lane = threadIdx.x;   // 0..63
    float4 v = ((const float4*)(cw + (size_t)k * C_DIM))[lane];
    union { unsigned short s[4]; uint2 d; } o;
    union { __hip_bfloat16 h; unsigned short u; } cv;
    cv.h = __float2bfloat16(v.x); o.s[0] = cv.u;
    cv.h = __float2bfloat16(v.y); o.s[1] = cv.u;
    cv.h = __float2bfloat16(v.z); o.s[2] = cv.u;
    cv.h = __float2bfloat16(v.w); o.s[3] = cv.u;
    unsigned short* cwb = (unsigned short*)(ws + WS_CWB);
    ((uint2*)(cwb + (size_t)k * C_DIM))[lane] = o.d;

    float sq = 0.f;
    sq = fmaf(v.x, v.x, sq); sq = fmaf(v.y, v.y, sq);
    sq = fmaf(v.z, v.z, sq); sq = fmaf(v.w, v.w, sq);
    sq += __shfl_xor(sq, 1);
    sq += __shfl_xor(sq, 2);
    sq += __shfl_xor(sq, 4);
    sq += __shfl_xor(sq, 8);
    sq += __shfl_xor(sq, 16);
    sq += __shfl_xor(sq, 32);
    if (lane == 0) ws[WS_C2 + k] = sq;
}

__global__ __launch_bounds__(256, 2)
void ce_main(const float* __restrict__ x,
             const float* __restrict__ scale,
             const float* __restrict__ ws_ro,
             float* __restrict__ Spart,
             float* __restrict__ a_part) {
    __shared__ float buf[2][4][16 * RS];   // 33 KB: per-wave double-buffered tiles
    __shared__ float sA[4][C_DIM];         // per-wave S partials
    __shared__ float awv[4][K_DIM];        // per-wave a partials
    __shared__ float f2s[4][64];           // per-wave f2 redistribution

    const int tid   = threadIdx.x;
    const int wave  = tid >> 6;
    const int lane  = tid & 63;
    const int g     = lane >> 4;   // 16-lane group (consume roles)
    const int m     = lane & 15;
    const int ig    = lane >> 4;   // load role: c-row group
    const int q     = lane & 15;   // load role: px-quad
    const int slice = blockIdx.x;  // 0..15
    const int b     = blockIdx.y;  // 0..31

    const float* xw   = x + (size_t)b * C_DIM * N_DIM + slice * 256 + wave * 64;
    const uint4* cwb4 = (const uint4*)(ws_ro + WS_CWB);
    const float* c2p  = ws_ro + WS_C2;

    float* b0 = &buf[0][wave][0];
    float* b1 = &buf[1][wave][0];

    v4f acc[2][4];
    #pragma unroll
    for (int u = 0; u < 2; ++u)
        #pragma unroll
        for (int t = 0; t < 4; ++t) acc[u][t] = (v4f){0.f, 0.f, 0.f, 0.f};

    float f2q[4] = {0.f, 0.f, 0.f, 0.f};
    float sLo[8], sHi[8];
    float4 xv[8];

    // A-fragment prefetch for s=0 (cw bf16, k = 16u+m, c = 8g..8g+7)
    uint4 af0 = cwb4[m * 32 + g];
    uint4 af1 = cwb4[(16 + m) * 32 + g];

    // prologue: load step 0 (rows i = 4*ig+j, c = 2i+r, px 4q..4q+3)
    #pragma unroll
    for (int j = 0; j < 4; ++j)
        #pragma unroll
        for (int r = 0; r < 2; ++r)
            xv[2 * j + r] = *(const float4*)(xw + (size_t)(2 * (4 * ig + j) + r) * N_DIM + 4 * q);
    // pack step 0 into tile0 (scalar unsigned LDS stores — same types as r5)
    #pragma unroll
    for (int j = 0; j < 4; ++j) {
        float4 r0 = xv[2 * j], r1 = xv[2 * j + 1];
        f2q[0] = fmaf(r0.x, r0.x, f2q[0]); f2q[0] = fmaf(r1.x, r1.x, f2q[0]);
        f2q[1] = fmaf(r0.y, r0.y, f2q[1]); f2q[1] = fmaf(r1.y, r1.y, f2q[1]);
        f2q[2] = fmaf(r0.z, r0.z, f2q[2]); f2q[2] = fmaf(r1.z, r1.z, f2q[2]);
        f2q[3] = fmaf(r0.w, r0.w, f2q[3]); f2q[3] = fmaf(r1.w, r1.w, f2q[3]);
        unsigned* dst = &((unsigned*)b0)[(4 * ig + j) * RS + 4 * q];
        dst[0] = pack_bf16(r0.x, r1.x);
        dst[1] = pack_bf16(r0.y, r1.y);
        dst[2] = pack_bf16(r0.z, r1.z);
        dst[3] = pack_bf16(r0.w, r1.w);
    }

    #pragma unroll
    for (int s = 0; s < 8; ++s) {
        float* cb = (s & 1) ? b1 : b0;
        float* nb = (s & 1) ? b0 : b1;

        // A-frag prefetch for s+1
        uint4 naf0, naf1;
        if (s < 7) {
            naf0 = cwb4[m * 32 + 4 * (s + 1) + g];
            naf1 = cwb4[(16 + m) * 32 + 4 * (s + 1) + g];
        }

        // issue next step's x loads (dwordx4; consumed by the pack below)
        if (s < 7) {
            #pragma unroll
            for (int j = 0; j < 4; ++j)
                #pragma unroll
                for (int r = 0; r < 2; ++r)
                    xv[2 * j + r] = *(const float4*)(xw +
                        (size_t)(32 * (s + 1) + 2 * (4 * ig + j) + r) * N_DIM + 4 * q);
        }

        // B-frags (f) + 8 MFMA: D[k][px] += cw[k][c] * f[c][px]
        #pragma unroll
        for (int t = 0; t < 4; ++t) {
            union { unsigned d[4]; v8s v; } fb;
            #pragma unroll
            for (int h = 0; h < 4; ++h)
                fb.d[h] = ((const unsigned*)cb)[(4 * g + h) * RS + 16 * t + m];
            union { uint4 u; v8s v; } a0, a1;
            a0.u = af0; a1.u = af1;
            acc[0][t] = __builtin_amdgcn_mfma_f32_16x16x32_bf16(a0.v, fb.v, acc[0][t], 0, 0, 0);
            acc[1][t] = __builtin_amdgcn_mfma_f32_16x16x32_bf16(a1.v, fb.v, acc[1][t], 0, 0, 0);
        }

        // S row sums from the staged tile: lane owns c-pair row m, px chunk 16g
        {
            float aLo = 0.f, aHi = 0.f;
            #pragma unroll
            for (int qq = 0; qq < 8; ++qq) {
                uint2 w = ((const uint2*)cb)[33 * m + 8 * g + qq];
                aLo += __uint_as_float(w.x << 16) + __uint_as_float(w.y << 16);
                aHi += __uint_as_float(w.x & 0xffff0000u) + __uint_as_float(w.y & 0xffff0000u);
            }
            aLo += __shfl_xor(aLo, 16); aLo += __shfl_xor(aLo, 32);
            aHi += __shfl_xor(aHi, 16); aHi += __shfl_xor(aHi, 32);
            sLo[s] = aLo; sHi[s] = aHi;
        }

        // pack the loads issued above into the next tile
        if (s < 7) {
            #pragma unroll
            for (int j = 0; j < 4; ++j) {
                float4 r0 = xv[2 * j], r1 = xv[2 * j + 1];
                f2q[0] = fmaf(r0.x, r0.x, f2q[0]); f2q[0] = fmaf(r1.x, r1.x, f2q[0]);
                f2q[1] = fmaf(r0.y, r0.y, f2q[1]); f2q[1] = fmaf(r1.y, r1.y, f2q[1]);
                f2q[2] = fmaf(r0.z, r0.z, f2q[2]); f2q[2] = fmaf(r1.z, r1.z, f2q[2]);
                f2q[3] = fmaf(r0.w, r0.w, f2q[3]); f2q[3] = fmaf(r1.w, r1.w, f2q[3]);
                unsigned* dst = &((unsigned*)nb)[(4 * ig + j) * RS + 4 * q];
                dst[0] = pack_bf16(r0.x, r1.x);
                dst[1] = pack_bf16(r0.y, r1.y);
                dst[2] = pack_bf16(r0.z, r1.z);
                dst[3] = pack_bf16(r0.w, r1.w);
            }
            af0 = naf0; af1 = naf1;
        }
    }

    // ---- epilogue: softmax over k (4-lane groups share a pixel) ----
    // f2 totals per px: reduce over the 4 ig-lanes sharing a px-quad
    #pragma unroll
    for (int p = 0; p < 4; ++p) {
        f2q[p] += __shfl_xor(f2q[p], 16);
        f2q[p] += __shfl_xor(f2q[p], 32);
    }
    if (lane < 16) {
        f2s[wave][4 * q + 0] = f2q[0];
        f2s[wave][4 * q + 1] = f2q[1];
        f2s[wave][4 * q + 2] = f2q[2];
        f2s[wave][4 * q + 3] = f2q[3];
    }

    float c2v[2][4], scv[2][4];
    #pragma unroll
    for (int u = 0; u < 2; ++u)
        #pragma unroll
        for (int r = 0; r < 4; ++r) {
            int k = 16 * u + 4 * g + r;
            c2v[u][r] = c2p[k];
            scv[u][r] = scale[k];
        }

    float aacc[2][4] = {{0.f,0.f,0.f,0.f},{0.f,0.f,0.f,0.f}};
    #pragma unroll
    for (int t = 0; t < 4; ++t) {
        float f2t = f2s[wave][16 * t + m];   // px = 16t + m
        float L[2][4];
        float mx = -1e30f;
        #pragma unroll
        for (int u = 0; u < 2; ++u)
            #pragma unroll
            for (int r = 0; r < 4; ++r) {
                float d2 = f2t + c2v[u][r] - 2.f * acc[u][t][r];
                float dist = sqrtf(fmaxf(d2, 0.f));
                float Lv = -dist * scv[u][r];
                L[u][r] = Lv;
                mx = fmaxf(mx, Lv);
            }
        mx = fmaxf(mx, __shfl_xor(mx, 16));
        mx = fmaxf(mx, __shfl_xor(mx, 32));
        float e[2][4], ss = 0.f;
        #pragma unroll
        for (int u = 0; u < 2; ++u)
            #pragma unroll
            for (int r = 0; r < 4; ++r) {
                e[u][r] = __expf(L[u][r] - mx);
                ss += e[u][r];
            }
        ss += __shfl_xor(ss, 16);
        ss += __shfl_xor(ss, 32);
        float inv = 1.f / ss;
        #pragma unroll
        for (int u = 0; u < 2; ++u)
            #pragma unroll
            for (int r = 0; r < 4; ++r)
                aacc[u][r] = fmaf(e[u][r], inv, aacc[u][r]);
    }

    // reduce a over the 16 pixels (m lanes) of each group
    #pragma unroll
    for (int u = 0; u < 2; ++u)
        #pragma unroll
        for (int r = 0; r < 4; ++r) {
            float v = aacc[u][r];
            v += __shfl_xor(v, 1);
            v += __shfl_xor(v, 2);
            v += __shfl_xor(v, 4);
            v += __shfl_xor(v, 8);
            if (m == 0) awv[wave][16 * u + 4 * g + r] = v;
        }

    if (g == 0) {
        #pragma unroll
        for (int s = 0; s < 8; ++s) {
            sA[wave][32 * s + 2 * m]     = sLo[s];
            sA[wave][32 * s + 2 * m + 1] = sHi[s];
        }
    }
    __syncthreads();

    float Ssum = sA[0][tid] + sA[1][tid] + sA[2][tid] + sA[3][tid];
    Spart[((size_t)b * NSLICE + slice) * C_DIM + tid] = Ssum;
    if (tid < K_DIM)
        a_part[((size_t)b * NSLICE + slice) * K_DIM + tid] =
            awv[0][tid] + awv[1][tid] + awv[2][tid] + awv[3][tid];
}

__global__ void ce_final(float* __restrict__ out,
                         const float* __restrict__ cw,
                         const float* __restrict__ Spart,
                         const float* __restrict__ a_part) {
    __shared__ float asum[K_DIM];
    const int b = blockIdx.x;
    const int c = threadIdx.x;

    if (c < K_DIM) {
        float a = 0.f;
        #pragma unroll
        for (int s = 0; s < NSLICE; ++s)
            a += a_part[((size_t)b * NSLICE + s) * K_DIM + c];
        asum[c] = a;
    }
    __syncthreads();

    float S = 0.f;
    #pragma unroll
    for (int s = 0; s < NSLICE; ++s)
        S += Spart[((size_t)b * NSLICE + s) * C_DIM + c];

    float acc2 = 0.f;
    #pragma unroll
    for (int k = 0; k < K_DIM; ++k)
        acc2 = fmaf(asum[k], cw[k * C_DIM + c], acc2);  // coalesced over c
    out[b * C_DIM + c] = (S - acc2) * (1.0f / (float)K_DIM);
}

extern "C" void kernel_launch(void* const* d_in, const int* in_sizes, int n_in,
                              void* d_out, int out_size, void* d_ws, size_t ws_size,
                              hipStream_t stream) {
    const float* x     = (const float*)d_in[0];
    const float* cw    = (const float*)d_in[1];
    const float* scale = (const float*)d_in[2];
    float* out = (float*)d_out;
    float* ws  = (float*)d_ws;

    ce_prep<<<K_DIM, 64, 0, stream>>>(cw, ws);

    dim3 grid(NSLICE, B_DIM);
    ce_main<<<grid, 256, 0, stream>>>(x, scale, ws,
                                      ws + WS_SPART, ws + WS_APART);

    ce_final<<<B_DIM, 256, 0, stream>>>(out, cw,
                                        ws + WS_SPART, ws + WS_APART);
}

// Round 13
// 40.503 us; speedup vs baseline: 1.5608x; 1.1069x over previous
//
#include <hip/hip_runtime.h>
#include <hip/hip_bf16.h>
#include <math.h>

// Problem dims (fixed per reference)
#define B_DIM 32
#define C_DIM 256
#define K_DIM 32
#define N_DIM 4096   // 64*64
#define NSLICE 16    // 256-px slices (4 waves x 64 px)
#define RS 66        // padded dword stride per c-pair row (16 rows/tile)

typedef short v8s __attribute__((ext_vector_type(8)));   // 8 bf16
typedef float v4f __attribute__((ext_vector_type(4)));   // MFMA acc

// ws float offsets — every slot overwritten each call, no zeroing, no atomics
//   [0,      131072)  Spart [B][16][C]
//   [131072, 147456)  a_part[B][16][K]
#define WS_SPART 0
#define WS_APART 131072

__device__ __forceinline__ unsigned pack_bf16(float lo, float hi) {
    union { __hip_bfloat16 h; unsigned short u; } a, b;
    a.h = __float2bfloat16(lo);
    b.h = __float2bfloat16(hi);
    return ((unsigned)b.u << 16) | a.u;
}

__global__ __launch_bounds__(256, 2)
void ce_main(const float* __restrict__ x,
             const float* __restrict__ cw,
             const float* __restrict__ scale,
             float* __restrict__ Spart,
             float* __restrict__ a_part) {
    __shared__ float buf[2][4][16 * RS];   // 33 KB: per-wave double-buffered tiles
    __shared__ unsigned cwl[K_DIM][132];   // 16.5 KB cw bf16-pairs (uint4-only access)
    __shared__ float sA[4][C_DIM];         // per-wave S partials
    __shared__ float awv[4][K_DIM];        // per-wave a partials
    __shared__ float f2s[4][64];           // per-wave f2 redistribution
    __shared__ float csl[64];              // c2[32] ++ scale[32]

    const int tid   = threadIdx.x;
    const int wave  = tid >> 6;
    const int lane  = tid & 63;
    const int g     = lane >> 4;   // 16-lane group (consume roles)
    const int m     = lane & 15;
    const int ig    = lane >> 4;   // load role: c-row group
    const int q     = lane & 15;   // load role: px-quad
    const int slice = blockIdx.x;  // 0..15
    const int b     = blockIdx.y;  // 0..31

    const float* xw = x + (size_t)b * C_DIM * N_DIM + slice * 256 + wave * 64;

    // ---- step-0 x loads FIRST (HBM latency hides under the cw staging) ----
    float4 xv[8];
    #pragma unroll
    for (int j = 0; j < 4; ++j)
        #pragma unroll
        for (int r = 0; r < 2; ++r)
            xv[2 * j + r] = *(const float4*)(xw + (size_t)(2 * (4 * ig + j) + r) * N_DIM + 4 * q);

    // ---- fused prep: cw fp32 -> bf16 LDS + c2 + scale (once per block) ----
    {
        const int r = tid >> 3, c8 = tid & 7;   // k-row 0..31, col-chunk of 32 c
        float4 cv[8];
        #pragma unroll
        for (int j = 0; j < 8; ++j)
            cv[j] = ((const float4*)(cw + (size_t)r * C_DIM + c8 * 32))[j];
        float sq = 0.f;
        #pragma unroll
        for (int j = 0; j < 8; ++j) {
            sq = fmaf(cv[j].x, cv[j].x, sq);
            sq = fmaf(cv[j].y, cv[j].y, sq);
            sq = fmaf(cv[j].z, cv[j].z, sq);
            sq = fmaf(cv[j].w, cv[j].w, sq);
        }
        sq += __shfl_xor(sq, 1);
        sq += __shfl_xor(sq, 2);
        sq += __shfl_xor(sq, 4);
        if (c8 == 0) csl[r] = sq;
        if (tid < K_DIM) csl[32 + tid] = scale[tid];
        #pragma unroll
        for (int w = 0; w < 4; ++w) {
            uint4 o;
            o.x = pack_bf16(cv[2 * w].x, cv[2 * w].y);
            o.y = pack_bf16(cv[2 * w].z, cv[2 * w].w);
            o.z = pack_bf16(cv[2 * w + 1].x, cv[2 * w + 1].y);
            o.w = pack_bf16(cv[2 * w + 1].z, cv[2 * w + 1].w);
            *(uint4*)&cwl[r][16 * c8 + 4 * w] = o;
        }
    }
    __syncthreads();

    // ---- hoist ALL A-fragments to registers (once; k = 16u+m, c-chunk 4s+g) ----
    uint4 afr[2][8];
    #pragma unroll
    for (int u = 0; u < 2; ++u)
        #pragma unroll
        for (int s = 0; s < 8; ++s)
            afr[u][s] = ((const uint4*)&cwl[16 * u + m][0])[4 * s + g];

    float* b0 = &buf[0][wave][0];
    float* b1 = &buf[1][wave][0];

    v4f acc[2][4];
    #pragma unroll
    for (int u = 0; u < 2; ++u)
        #pragma unroll
        for (int t = 0; t < 4; ++t) acc[u][t] = (v4f){0.f, 0.f, 0.f, 0.f};

    float f2q[4] = {0.f, 0.f, 0.f, 0.f};
    float sLo[8], sHi[8];

    // pack step 0 into tile0 (scalar unsigned LDS stores — proven type combo)
    #pragma unroll
    for (int j = 0; j < 4; ++j) {
        float4 r0 = xv[2 * j], r1 = xv[2 * j + 1];
        f2q[0] = fmaf(r0.x, r0.x, f2q[0]); f2q[0] = fmaf(r1.x, r1.x, f2q[0]);
        f2q[1] = fmaf(r0.y, r0.y, f2q[1]); f2q[1] = fmaf(r1.y, r1.y, f2q[1]);
        f2q[2] = fmaf(r0.z, r0.z, f2q[2]); f2q[2] = fmaf(r1.z, r1.z, f2q[2]);
        f2q[3] = fmaf(r0.w, r0.w, f2q[3]); f2q[3] = fmaf(r1.w, r1.w, f2q[3]);
        unsigned* dst = &((unsigned*)b0)[(4 * ig + j) * RS + 4 * q];
        dst[0] = pack_bf16(r0.x, r1.x);
        dst[1] = pack_bf16(r0.y, r1.y);
        dst[2] = pack_bf16(r0.z, r1.z);
        dst[3] = pack_bf16(r0.w, r1.w);
    }

    #pragma unroll
    for (int s = 0; s < 8; ++s) {
        float* cb = (s & 1) ? b1 : b0;
        float* nb = (s & 1) ? b0 : b1;

        // issue next step's x loads (dwordx4; consumed by the pack below)
        if (s < 7) {
            #pragma unroll
            for (int j = 0; j < 4; ++j)
                #pragma unroll
                for (int r = 0; r < 2; ++r)
                    xv[2 * j + r] = *(const float4*)(xw +
                        (size_t)(32 * (s + 1) + 2 * (4 * ig + j) + r) * N_DIM + 4 * q);
        }

        // B-frags (f) + 8 MFMA: D[k][px] += cw[k][c] * f[c][px]
        #pragma unroll
        for (int t = 0; t < 4; ++t) {
            union { unsigned d[4]; v8s v; } fb;
            #pragma unroll
            for (int h = 0; h < 4; ++h)
                fb.d[h] = ((const unsigned*)cb)[(4 * g + h) * RS + 16 * t + m];
            union { uint4 u; v8s v; } a0, a1;
            a0.u = afr[0][s]; a1.u = afr[1][s];
            acc[0][t] = __builtin_amdgcn_mfma_f32_16x16x32_bf16(a0.v, fb.v, acc[0][t], 0, 0, 0);
            acc[1][t] = __builtin_amdgcn_mfma_f32_16x16x32_bf16(a1.v, fb.v, acc[1][t], 0, 0, 0);
        }

        // S row sums from the staged tile: lane owns c-pair row m, px chunk 16g
        {
            float aLo = 0.f, aHi = 0.f;
            #pragma unroll
            for (int qq = 0; qq < 8; ++qq) {
                uint2 w = ((const uint2*)cb)[33 * m + 8 * g + qq];
                aLo += __uint_as_float(w.x << 16) + __uint_as_float(w.y << 16);
                aHi += __uint_as_float(w.x & 0xffff0000u) + __uint_as_float(w.y & 0xffff0000u);
            }
            aLo += __shfl_xor(aLo, 16); aLo += __shfl_xor(aLo, 32);
            aHi += __shfl_xor(aHi, 16); aHi += __shfl_xor(aHi, 32);
            sLo[s] = aLo; sHi[s] = aHi;
        }

        // pack the loads issued above into the next tile
        if (s < 7) {
            #pragma unroll
            for (int j = 0; j < 4; ++j) {
                float4 r0 = xv[2 * j], r1 = xv[2 * j + 1];
                f2q[0] = fmaf(r0.x, r0.x, f2q[0]); f2q[0] = fmaf(r1.x, r1.x, f2q[0]);
                f2q[1] = fmaf(r0.y, r0.y, f2q[1]); f2q[1] = fmaf(r1.y, r1.y, f2q[1]);
                f2q[2] = fmaf(r0.z, r0.z, f2q[2]); f2q[2] = fmaf(r1.z, r1.z, f2q[2]);
                f2q[3] = fmaf(r0.w, r0.w, f2q[3]); f2q[3] = fmaf(r1.w, r1.w, f2q[3]);
                unsigned* dst = &((unsigned*)nb)[(4 * ig + j) * RS + 4 * q];
                dst[0] = pack_bf16(r0.x, r1.x);
                dst[1] = pack_bf16(r0.y, r1.y);
                dst[2] = pack_bf16(r0.z, r1.z);
                dst[3] = pack_bf16(r0.w, r1.w);
            }
        }
    }

    // ---- epilogue: softmax over k (4-lane groups share a pixel) ----
    // f2 totals per px: reduce over the 4 ig-lanes sharing a px-quad
    #pragma unroll
    for (int p = 0; p < 4; ++p) {
        f2q[p] += __shfl_xor(f2q[p], 16);
        f2q[p] += __shfl_xor(f2q[p], 32);
    }
    if (lane < 16) {
        f2s[wave][4 * q + 0] = f2q[0];
        f2s[wave][4 * q + 1] = f2q[1];
        f2s[wave][4 * q + 2] = f2q[2];
        f2s[wave][4 * q + 3] = f2q[3];
    }

    float c2v[2][4], scv[2][4];
    #pragma unroll
    for (int u = 0; u < 2; ++u)
        #pragma unroll
        for (int r = 0; r < 4; ++r) {
            int k = 16 * u + 4 * g + r;
            c2v[u][r] = csl[k];
            scv[u][r] = csl[32 + k];
        }

    float aacc[2][4] = {{0.f,0.f,0.f,0.f},{0.f,0.f,0.f,0.f}};
    #pragma unroll
    for (int t = 0; t < 4; ++t) {
        float f2t = f2s[wave][16 * t + m];   // px = 16t + m
        float L[2][4];
        float mx = -1e30f;
        #pragma unroll
        for (int u = 0; u < 2; ++u)
            #pragma unroll
            for (int r = 0; r < 4; ++r) {
                float d2 = f2t + c2v[u][r] - 2.f * acc[u][t][r];
                float dist = sqrtf(fmaxf(d2, 0.f));
                float Lv = -dist * scv[u][r];
                L[u][r] = Lv;
                mx = fmaxf(mx, Lv);
            }
        mx = fmaxf(mx, __shfl_xor(mx, 16));
        mx = fmaxf(mx, __shfl_xor(mx, 32));
        float e[2][4], ss = 0.f;
        #pragma unroll
        for (int u = 0; u < 2; ++u)
            #pragma unroll
            for (int r = 0; r < 4; ++r) {
                e[u][r] = __expf(L[u][r] - mx);
                ss += e[u][r];
            }
        ss += __shfl_xor(ss, 16);
        ss += __shfl_xor(ss, 32);
        float inv = 1.f / ss;
        #pragma unroll
        for (int u = 0; u < 2; ++u)
            #pragma unroll
            for (int r = 0; r < 4; ++r)
                aacc[u][r] = fmaf(e[u][r], inv, aacc[u][r]);
    }

    // reduce a over the 16 pixels (m lanes) of each group
    #pragma unroll
    for (int u = 0; u < 2; ++u)
        #pragma unroll
        for (int r = 0; r < 4; ++r) {
            float v = aacc[u][r];
            v += __shfl_xor(v, 1);
            v += __shfl_xor(v, 2);
            v += __shfl_xor(v, 4);
            v += __shfl_xor(v, 8);
            if (m == 0) awv[wave][16 * u + 4 * g + r] = v;
        }

    if (g == 0) {
        #pragma unroll
        for (int s = 0; s < 8; ++s) {
            sA[wave][32 * s + 2 * m]     = sLo[s];
            sA[wave][32 * s + 2 * m + 1] = sHi[s];
        }
    }
    __syncthreads();

    float Ssum = sA[0][tid] + sA[1][tid] + sA[2][tid] + sA[3][tid];
    Spart[((size_t)b * NSLICE + slice) * C_DIM + tid] = Ssum;
    if (tid < K_DIM)
        a_part[((size_t)b * NSLICE + slice) * K_DIM + tid] =
            awv[0][tid] + awv[1][tid] + awv[2][tid] + awv[3][tid];
}

__global__ void ce_final(float* __restrict__ out,
                         const float* __restrict__ cw,
                         const float* __restrict__ Spart,
                         const float* __restrict__ a_part) {
    __shared__ float asum[K_DIM];
    const int b = blockIdx.x;
    const int c = threadIdx.x;

    if (c < K_DIM) {
        float a = 0.f;
        #pragma unroll
        for (int s = 0; s < NSLICE; ++s)
            a += a_part[((size_t)b * NSLICE + s) * K_DIM + c];
        asum[c] = a;
    }
    __syncthreads();

    float S = 0.f;
    #pragma unroll
    for (int s = 0; s < NSLICE; ++s)
        S += Spart[((size_t)b * NSLICE + s) * C_DIM + c];

    float acc2 = 0.f;
    #pragma unroll
    for (int k = 0; k < K_DIM; ++k)
        acc2 = fmaf(asum[k], cw[k * C_DIM + c], acc2);  // coalesced over c
    out[b * C_DIM + c] = (S - acc2) * (1.0f / (float)K_DIM);
}

extern "C" void kernel_launch(void* const* d_in, const int* in_sizes, int n_in,
                              void* d_out, int out_size, void* d_ws, size_t ws_size,
                              hipStream_t stream) {
    const float* x     = (const float*)d_in[0];
    const float* cw    = (const float*)d_in[1];
    const float* scale = (const float*)d_in[2];
    float* out = (float*)d_out;
    float* ws  = (float*)d_ws;

    dim3 grid(NSLICE, B_DIM);
    ce_main<<<grid, 256, 0, stream>>>(x, cw, scale,
                                      ws + WS_SPART, ws + WS_APART);

    ce_final<<<B_DIM, 256, 0, stream>>>(out, cw,
                                        ws + WS_SPART, ws + WS_APART);
}